// Round 1
// baseline (682.220 us; speedup 1.0000x reference)
//
#include <hip/hip_runtime.h>
#include <math.h>

// Problem constants (from reference: x[8,2048,1024] f32, W[1024,64] f32)
#define BB 8
#define NN 2048
#define DD 1024
#define EE 64
#define CAP 64
#define NTOK (BB * NN)          // 16384
#define OUT_T_FLOATS 67108864   // 8*2048*64*64 per tensor
#define OUT_T_F4     16777216   // float4 count per tensor

// Workspace layout (bytes):
//   recs      float4[NTOK]   @ 0        {g1n, g2n, bits(i1), bits(i2 | flag<<8)}
//   frecs     float4[NTOK]   @ 262144   {g1 or 0, g2 or 0, bits(e1*64+c1 or -1), bits(e2*64+c2 or -1)}
//   dens      float[512*64]  @ 524288   per-block density partial sums
//   lossp     float[8]       @ 655360   per-batch loss partials

// ---------------------------------------------------------------------------
// Kernel G: logits GEMM + softmax + top2 + gates + density partials.
// Block = 256 threads (4 waves). Wave handles 8 consecutive tokens;
// lane j owns expert j. W chunk [64d x 64e] staged in LDS; x reads are
// wave-uniform (tok0 forced uniform via readfirstlane) -> scalar loads.
// ---------------------------------------------------------------------------
__global__ __launch_bounds__(256) void gating_kernel(
    const float* __restrict__ x, const float* __restrict__ W,
    float4* __restrict__ recs, float* __restrict__ dens)
{
    __shared__ float Wl[64 * 64];     // 16 KB
    __shared__ float dred[4][64];

    const int lane = threadIdx.x & 63;
    const int wave = __builtin_amdgcn_readfirstlane(threadIdx.x >> 6);
    const int tok0 = blockIdx.x * 32 + wave * 8;
    const float* xr = x + (size_t)tok0 * DD;

    float acc[8];
#pragma unroll
    for (int t = 0; t < 8; ++t) acc[t] = 0.f;

    for (int dc = 0; dc < 16; ++dc) {
        __syncthreads();
        {   // stage W rows [dc*64, dc*64+64) -- 4096 floats, coalesced
            const float4* wg = (const float4*)(W + dc * 64 * 64);
            float4* wl = (float4*)Wl;
#pragma unroll
            for (int k = 0; k < 4; ++k)
                wl[threadIdx.x + 256 * k] = wg[threadIdx.x + 256 * k];
        }
        __syncthreads();
        const float* xc = xr + dc * 64;
#pragma unroll 8
        for (int dd = 0; dd < 64; ++dd) {
            float w = Wl[dd * 64 + lane];      // stride-1 across lanes: conflict-free
#pragma unroll
            for (int t = 0; t < 8; ++t)
                acc[t] = fmaf(xc[(size_t)t * DD + dd], w, acc[t]);  // x uniform -> s_load
        }
    }

    float densacc = 0.f;
#pragma unroll 1
    for (int t = 0; t < 8; ++t) {
        const float lv = acc[t];
        // argmax (value desc, index asc on ties) -- matches jnp.argmax first-max
        float v = lv; int bi = lane;
#pragma unroll
        for (int off = 32; off; off >>= 1) {
            float ov = __shfl_xor(v, off);
            int   oi = __shfl_xor(bi, off);
            if (ov > v || (ov == v && oi < bi)) { v = ov; bi = oi; }
        }
        const float m1 = v; const int i1 = bi;
        float v2 = (lane == i1) ? -INFINITY : lv; int b2 = lane;
#pragma unroll
        for (int off = 32; off; off >>= 1) {
            float ov = __shfl_xor(v2, off);
            int   oi = __shfl_xor(b2, off);
            if (ov > v2 || (ov == v2 && oi < b2)) { v2 = ov; b2 = oi; }
        }
        const float m2 = v2; const int i2 = b2;

        float ex = expf(lv - m1);
        float Z = ex;
#pragma unroll
        for (int off = 32; off; off >>= 1) Z += __shfl_xor(Z, off);
        float g1 = 1.0f / Z;               // exp(m1-m1)/Z
        float g2 = expf(m2 - m1) * g1;     // p[i2]
        float den = g1 + g2 + 1e-9f;
        float g1n = g1 / den;
        float g2n = g2 / den;
        int flag = (g2n > 0.2f) ? 1 : 0;   // threshold on normalized gate_2

        densacc += ex * g1;                // p_t[lane] for density proxy

        if (lane == 0)
            recs[tok0 + t] = make_float4(g1n, g2n, __int_as_float(i1),
                                         __int_as_float(i2 | (flag << 8)));
    }

    dred[wave][lane] = densacc;
    __syncthreads();
    if (wave == 0) {
        float s = dred[0][lane] + dred[1][lane] + dred[2][lane] + dred[3][lane];
        dens[blockIdx.x * 64 + lane] = s;  // per-block partial, no atomics
    }
}

// ---------------------------------------------------------------------------
// Kernel S: per-batch hierarchical scan for position-in-expert, capacity
// trim, mask_1_count base for pass 2, loss partial. 1 block per batch,
// 1024 threads = 16 waves; wave w scans tokens [w*128, w*128+128).
// ---------------------------------------------------------------------------
__global__ __launch_bounds__(1024) void scan_kernel(
    const float4* __restrict__ recs, const float* __restrict__ dens,
    float4* __restrict__ frecs, float* __restrict__ lossp)
{
    const int b = blockIdx.x;
    __shared__ short i1s[NN], i2s[NN];
    __shared__ unsigned char fls[NN];
    __shared__ short p1loc[NN], p2loc[NN];
    __shared__ int hist1[16][64], pre1[16][64], hist2[16][64], pre2[16][64];
    __shared__ int base2[64], total1[64];
    __shared__ float dsum[64];

    const int tid = threadIdx.x;
    const int lane = tid & 63;
    const int wave = tid >> 6;

    for (int i = tid; i < NN; i += 1024) {
        float4 r = recs[b * NN + i];
        int i1  = __float_as_int(r.z);
        int i2f = __float_as_int(r.w);
        i1s[i] = (short)i1;
        i2s[i] = (short)(i2f & 63);
        fls[i] = (unsigned char)(i2f >> 8);
        p2loc[i] = 0;
    }
    if (tid < 64) {  // density sums for this batch (uncapped proxy)
        float s = 0.f;
        for (int k = 0; k < 64; ++k) s += dens[(b * 64 + k) * 64 + tid];
        dsum[tid] = s;
    }
    __syncthreads();

    {   // local sequential scans: lane j holds running count for expert j
        const int base = wave * 128;
        int cnt = 0;
        for (int i = 0; i < 128; ++i) {
            int e1 = i1s[base + i];                 // LDS broadcast read
            if (lane == e1) { p1loc[base + i] = (short)cnt; ++cnt; }
        }
        hist1[wave][lane] = cnt;
        int cnt2 = 0;
        for (int i = 0; i < 128; ++i) {
            int ok = fls[base + i];
            int e2 = i2s[base + i];
            if (ok && lane == e2) { p2loc[base + i] = (short)cnt2; ++cnt2; }
        }
        hist2[wave][lane] = cnt2;
    }
    __syncthreads();

    if (wave == 0) {   // cross-wave exclusive prefix per expert (lane = expert)
        int run = 0;
#pragma unroll
        for (int w = 0; w < 16; ++w) { pre1[w][lane] = run; run += hist1[w][lane]; }
        total1[lane] = run;                       // UNCAPPED count (for loss)
        base2[lane] = run < CAP ? run : CAP;      // mask_1_count = min(count, cap)
        int run2 = 0;
#pragma unroll
        for (int w = 0; w < 16; ++w) { pre2[w][lane] = run2; run2 += hist2[w][lane]; }
        // loss partial: sum_e dens_sum[e] * count_e
        float v = dsum[lane] * (float)run;
#pragma unroll
        for (int off = 32; off; off >>= 1) v += __shfl_xor(v, off);
        if (lane == 0) lossp[b] = v;
    }
    __syncthreads();

    for (int i = tid; i < NN; i += 1024) {
        int w = i >> 7;
        float4 r = recs[b * NN + i];
        int e1 = i1s[i];
        int p1 = (int)p1loc[i] + pre1[w][e1];
        int k1 = p1 < CAP;
        int e2 = i2s[i];
        int fl = fls[i];
        int p2 = (int)p2loc[i] + pre2[w][e2] + base2[e2];
        int k2 = fl && (p2 < CAP);
        float4 fr;
        fr.x = k1 ? r.x : 0.f;
        fr.y = k2 ? r.y : 0.f;
        fr.z = __int_as_float(k1 ? (e1 * CAP + p1) : -1);
        fr.w = __int_as_float(k2 ? (e2 * CAP + p2) : -1);
        frecs[b * NN + i] = fr;
    }
}

// ---------------------------------------------------------------------------
// Kernel F: write all 537 MB of dispatch+combine in one coalesced pass.
// Thread handles one float4 of dispatch (tid) and the matching float4 of
// combine (tid + 16M). 1024 threads per token slab (64 e x 16 c4).
// ---------------------------------------------------------------------------
__global__ __launch_bounds__(256) void fill_kernel(
    const float4* __restrict__ frecs, const float* __restrict__ lossp,
    float* __restrict__ out)
{
    const int tid = blockIdx.x * 256 + threadIdx.x;   // 0 .. 16777215
    const int token = tid >> 10;
    const int e  = (tid >> 4) & 63;
    const int c4 = tid & 15;
    float4 r = frecs[token];   // broadcast across 1024 threads -> L1 hit

    float cx = 0.f, cy = 0.f, cz = 0.f, cw = 0.f;
    float dx = 0.f, dy = 0.f, dz = 0.f, dw = 0.f;

    int p1 = __float_as_int(r.z);
    if (p1 >= 0 && (p1 >> 6) == e && ((p1 >> 2) & 15) == c4) {
        int cc = p1 & 3;
        if      (cc == 0) { cx = r.x; dx = 1.f; }
        else if (cc == 1) { cy = r.x; dy = 1.f; }
        else if (cc == 2) { cz = r.x; dz = 1.f; }
        else              { cw = r.x; dw = 1.f; }
    }
    int p2 = __float_as_int(r.w);
    if (p2 >= 0 && (p2 >> 6) == e && ((p2 >> 2) & 15) == c4) {
        int cc = p2 & 3;
        if      (cc == 0) { cx = r.y; dx = 1.f; }
        else if (cc == 1) { cy = r.y; dy = 1.f; }
        else if (cc == 2) { cz = r.y; dz = 1.f; }
        else              { cw = r.y; dw = 1.f; }
    }

    float4* o4 = (float4*)out;
    o4[tid]             = make_float4(dx, dy, dz, dw);   // dispatch
    o4[tid + OUT_T_F4]  = make_float4(cx, cy, cz, cw);   // combine

    if (tid == 0) {
        float s = 0.f;
        for (int k = 0; k < 8; ++k) s += lossp[k];
        // loss = sum_{b,e}(sumgates*count) * e^2 / (b*e*n^2) = s / 524288
        out[2 * OUT_T_FLOATS] = s * (1.0f / 524288.0f);
    }
}

extern "C" void kernel_launch(void* const* d_in, const int* in_sizes, int n_in,
                              void* d_out, int out_size, void* d_ws, size_t ws_size,
                              hipStream_t stream)
{
    const float* x = (const float*)d_in[0];
    const float* W = (const float*)d_in[1];
    float* out = (float*)d_out;
    char* ws = (char*)d_ws;

    float4* recs  = (float4*)(ws);
    float4* frecs = (float4*)(ws + 262144);
    float*  dens  = (float*)(ws + 524288);
    float*  lossp = (float*)(ws + 655360);

    gating_kernel<<<512, 256, 0, stream>>>(x, W, recs, dens);
    scan_kernel<<<8, 1024, 0, stream>>>(recs, dens, frecs, lossp);
    fill_kernel<<<65536, 256, 0, stream>>>(frecs, lossp, out);
}